// Round 7
// baseline (95.845 us; speedup 1.0000x reference)
//
#include <hip/hip_runtime.h>
#include <hip/hip_bf16.h>

// NT-Xent (SimCLR) loss, MI355X gfx950.
// loss = (1/N) * sum_i [ ln(S_i - exp2(C1*d_ii)) - (2/C1)*dp_i ]
//   where d = zhat.zhat^T (unit rows), C1 = 2*log2(e),
//   S_i = sum_j exp2(C1*d_ij), dp_i = C1 * d_{i, i^B}.
// zb stores sqrt(C1)*zhat in bf16, pre-swizzled into MFMA fragment order:
// 16B chunk for (tile=row>>4, c, lane=quad*16+t) at uint4 index
//   (tile*4+c)*64 + lane, covering row=tile*16+t, k in [c*32+quad*8, +8).
// R7: triangular sweep with FINE 128x128 blocks (64 strips, 2080 blocks).
// R6 lesson: 256x256 triangular blocks quantized to 2 generations (528
// blocks @ 512 slots -> 94% tail) and erased the 2x work saving. 128x128
// blocks give 3-4 blocks/CU and a ~3% tail. sim is symmetric (identical zb
// both sides -> bitwise-equal exp), so blocks (p,q) p<=q emit row sums
// (partR[q]) and mirrored col sums (partC[p]).
// R5 kept: B-span staged in LDS via global_load_lds width=16.
// R4 lesson: watch WRITE_SIZE for scratch-spill ballooning.

#define NN 8192
#define BHALF 4096
#define DIMK 128

typedef __bf16 bf16x8 __attribute__((ext_vector_type(8)));
typedef float f32x4 __attribute__((ext_vector_type(4)));

#define C1F 2.8853900817779268f   // 2*log2(e)
#define SCALEF 1.6986436f         // sqrt(C1)

// ---------------- Kernel A: normalize, scale by sqrt(C1), swizzle ----------
__global__ __launch_bounds__(256) void nt_normalize(
    const float* __restrict__ zi, const float* __restrict__ zj,
    unsigned int* __restrict__ zb_packed, float* __restrict__ out) {
  if (blockIdx.x == 0 && threadIdx.x == 0) out[0] = 0.0f;  // runs before finalize
  int row = blockIdx.x * 4 + (threadIdx.x >> 6);
  int lane = threadIdx.x & 63;
  const float* src = (row < BHALF) ? (zi + (size_t)row * DIMK)
                                   : (zj + (size_t)(row - BHALF) * DIMK);
  float2 v = ((const float2*)src)[lane];
  float ss = v.x * v.x + v.y * v.y;
#pragma unroll
  for (int off = 32; off >= 1; off >>= 1) ss += __shfl_xor(ss, off, 64);
  float rn = rsqrtf(ss) * SCALEF;
  __hip_bfloat16 h0 = __float2bfloat16(v.x * rn);
  __hip_bfloat16 h1 = __float2bfloat16(v.y * rn);
  unsigned int packed = ((unsigned int)(*(unsigned short*)&h1) << 16) |
                        (*(unsigned short*)&h0);
  int tile = row >> 4, t = row & 15;
  int cq = lane >> 2;               // chunk index 0..15 (= c*4 + quad)
  int c = cq >> 2, quad = cq & 3;
  size_t widx = ((size_t)((tile * 4 + c) * 64 + quad * 16 + t)) * 4 + (lane & 3);
  zb_packed[widx] = packed;
}

// ---------------- Kernel B: triangular sim + exp2 accumulation -------------
// 2080 blocks, bid -> (p,q), p<=q, strips of 128 rows/cols.
// Block = 4 waves x 32 rows = 128 rows of strip p; 128 cols of strip q in LDS.
// C/D: col=lane&15, row=quad*4+reg.
__global__ __launch_bounds__(256, 3) void nt_sim(
    const uint4* __restrict__ zbv, float* __restrict__ partR,
    float* __restrict__ partC) {
  __shared__ uint4 ldsb[2048];      // 32 KiB: B-span (cols strip q)
  __shared__ float colbuf[4][128];  // 2 KiB: per-wave col partials

  const int bid = blockIdx.x;
  // invert f(p) = p*(129-p)/2 (blocks before strip p), 64 strips
  int p = (int)((129.0f - sqrtf(16641.0f - 8.0f * (float)bid)) * 0.5f);
  while (p > 0 && p * (129 - p) / 2 > bid) --p;
  while ((p + 1) * (128 - p) / 2 <= bid) ++p;
  const int q = p + (bid - p * (129 - p) / 2);

  const int lane = threadIdx.x & 63;
  const int wave = threadIdx.x >> 6;
  const int quad = lane >> 4;
  const int t = lane & 15;
  const int row_tile0 = p * 8 + wave * 2;

  // ---- async-stage strip q's 32KB B-span: 32 chunks of 1KB, 8/wave ----
  {
    const char* gsrc = (const char*)zbv + (size_t)q * 32768;
#pragma unroll
    for (int k = 0; k < 8; ++k) {
      int chunk = k * 4 + wave;
      __builtin_amdgcn_global_load_lds(
          (const __attribute__((address_space(1))) unsigned int*)(
              gsrc + chunk * 1024 + lane * 16),
          (__attribute__((address_space(3))) unsigned int*)(
              (char*)ldsb + chunk * 1024),
          16, 0, 0);
    }
  }

  // ---- A fragments (persistent registers), overlaps with DMA ----
  bf16x8 A[2][4];  // [row-tile][K-chunk]
#pragma unroll
  for (int rt = 0; rt < 2; ++rt)
#pragma unroll
    for (int c = 0; c < 4; ++c)
      A[rt][c] = __builtin_bit_cast(
          bf16x8, zbv[(size_t)((row_tile0 + rt) * 4 + c) * 64 + lane]);

  float sum[2][4];
#pragma unroll
  for (int rt = 0; rt < 2; ++rt)
#pragma unroll
    for (int r = 0; r < 4; ++r) sum[rt][r] = 0.f;
  float colw[8];

  __syncthreads();  // DMA drain + join

  // ---- compute loop: 8 col-tiles from LDS ----
#pragma unroll 2
  for (int ct = 0; ct < 8; ++ct) {
    f32x4 acc[2];
    acc[0] = (f32x4){0.f, 0.f, 0.f, 0.f};
    acc[1] = (f32x4){0.f, 0.f, 0.f, 0.f};
#pragma unroll
    for (int c = 0; c < 4; ++c) {
      bf16x8 bv = __builtin_bit_cast(bf16x8, ldsb[(ct * 4 + c) * 64 + lane]);
      acc[0] = __builtin_amdgcn_mfma_f32_16x16x32_bf16(A[0][c], bv, acc[0],
                                                       0, 0, 0);
      acc[1] = __builtin_amdgcn_mfma_f32_16x16x32_bf16(A[1][c], bv, acc[1],
                                                       0, 0, 0);
    }
    float cp = 0.f;
#pragma unroll
    for (int rt = 0; rt < 2; ++rt)
#pragma unroll
      for (int r = 0; r < 4; ++r) {
        float e = __builtin_amdgcn_exp2f(acc[rt][r]);
        sum[rt][r] += e;
        cp += e;
      }
    colw[ct] = cp;  // col partial over this lane's 8 rows
  }

  // ---- row sums: reduce over the 16 col-lanes within each quad ----
#pragma unroll
  for (int off = 8; off >= 1; off >>= 1)
#pragma unroll
    for (int rt = 0; rt < 2; ++rt)
#pragma unroll
      for (int r = 0; r < 4; ++r)
        sum[rt][r] += __shfl_xor(sum[rt][r], off, 16);

  if (t == 0) {
    float* dst = partR + (size_t)q * NN + p * 128 + wave * 32;
#pragma unroll
    for (int rt = 0; rt < 2; ++rt)
#pragma unroll
      for (int r = 0; r < 4; ++r)
        dst[rt * 16 + quad * 4 + r] = sum[rt][r];
  }

  // ---- col sums (off-diagonal blocks only) ----
  if (p != q) {
    // reduce colw over the 4 quads (rows): each lane ends with 32-row sum
#pragma unroll
    for (int ct = 0; ct < 8; ++ct) {
      colw[ct] += __shfl_xor(colw[ct], 16, 64);
      colw[ct] += __shfl_xor(colw[ct], 32, 64);
    }
    if (quad == 0) {
#pragma unroll
      for (int ct = 0; ct < 8; ++ct) colbuf[wave][ct * 16 + t] = colw[ct];
    }
    __syncthreads();  // block-uniform branch: legal
    if (threadIdx.x < 128) {
      int cidx = threadIdx.x;
      partC[(size_t)p * NN + q * 128 + cidx] =
          colbuf[0][cidx] + colbuf[1][cidx] + colbuf[2][cidx] + colbuf[3][cidx];
    }
  }
}

// ---------------- Kernel C: finalize ----------------
__device__ __forceinline__ float bf2f(unsigned short s) {
  unsigned int u = (unsigned int)s << 16;
  return __builtin_bit_cast(float, u);
}

__global__ __launch_bounds__(256) void nt_finalize(
    const uint4* __restrict__ zbv, const float* __restrict__ partR,
    const float* __restrict__ partC, float* __restrict__ out) {
  int i = blockIdx.x * 256 + threadIdx.x;
  int s = i >> 7;  // strip of row i (128 rows per strip)
  int tile = i >> 4, t = i & 15;
  int pr = i ^ BHALF;
  int tilep = pr >> 4;
  float S = 0.f;
  for (int k = s; k < 64; ++k) S += partR[(size_t)k * NN + i];
  for (int k = 0; k < s; ++k) S += partC[(size_t)k * NN + i];
  float dp = 0.f, dd = 0.f;
#pragma unroll
  for (int cq = 0; cq < 16; ++cq) {
    int c = cq >> 2, qq = cq & 3;
    uint4 ua = zbv[(size_t)((tile * 4 + c) * 64 + qq * 16 + t)];
    uint4 up = zbv[(size_t)((tilep * 4 + c) * 64 + qq * 16 + t)];
    const unsigned short* pa = (const unsigned short*)&ua;
    const unsigned short* pp = (const unsigned short*)&up;
#pragma unroll
    for (int k = 0; k < 8; ++k) {
      float a = bf2f(pa[k]), pv = bf2f(pp[k]);
      dd = fmaf(a, a, dd);
      dp = fmaf(a, pv, dp);
    }
  }
  float diag = __builtin_amdgcn_exp2f(dd);        // exp2(C1 * d_ii)
  float v = logf(S - diag) - (2.0f / C1F) * dp;   // lse_i - pos_i
#pragma unroll
  for (int off = 32; off >= 1; off >>= 1) v += __shfl_xor(v, off, 64);
  __shared__ float wsum[4];
  if ((threadIdx.x & 63) == 0) wsum[threadIdx.x >> 6] = v;
  __syncthreads();
  if (threadIdx.x == 0)
    atomicAdd(out, (wsum[0] + wsum[1] + wsum[2] + wsum[3]) * (1.0f / (float)NN));
}

extern "C" void kernel_launch(void* const* d_in, const int* in_sizes, int n_in,
                              void* d_out, int out_size, void* d_ws,
                              size_t ws_size, hipStream_t stream) {
  const float* zi = (const float*)d_in[0];
  const float* zj = (const float*)d_in[1];

  // ws: zb swizzled bf16 (2 MiB) | partR[64][8192] (2 MiB) | partC[64][8192]
  unsigned int* zb = (unsigned int*)d_ws;
  float* partR = (float*)((char*)d_ws + (2u << 20));
  float* partC = (float*)((char*)d_ws + (4u << 20));

  nt_normalize<<<NN / 4, 256, 0, stream>>>(zi, zj, zb, (float*)d_out);

  nt_sim<<<2080, 256, 0, stream>>>((const uint4*)zb, partR, partC);

  nt_finalize<<<NN / 256, 256, 0, stream>>>((const uint4*)zb, partR, partC,
                                            (float*)d_out);
}

// Round 8
// 83.477 us; speedup vs baseline: 1.1482x; 1.1482x over previous
//
#include <hip/hip_runtime.h>
#include <hip/hip_bf16.h>

// NT-Xent (SimCLR) loss, MI355X gfx950.
// loss = (1/N) * sum_i [ ln(S_i - exp2(C1*d_ii)) - (2/C1)*dp_i ]
//   where d = zhat.zhat^T (unit rows), C1 = 2*log2(e),
//   S_i = sum_j exp2(C1*d_ij), dp_i = C1 * d_{i, i^B}.
// zb stores sqrt(C1)*zhat in bf16, pre-swizzled into MFMA fragment order:
// 16B chunk for (tile=row>>4, c, lane=quad*16+t) at uint4 index
//   (tile*4+c)*64 + lane, covering row=tile*16+t, k in [c*32+quad*8, +8).
// R8: back to R5's FULL sweep (triangular lost twice to scheduling overhead).
// Occupancy lever: 128-col span (32 KB LDS) + launch_bounds(256,4) ->
// 4 blocks/CU = 4 waves/SIMD (R5 had 2). Latency-bound diagnosis: R5's
// floors are MFMA 2.1us / VALU 4.3us / LDS 3.4us but measured ~20us.
// unroll 1 on the col-tile loop to stay under the 128-VGPR cap; TLP (not
// ILP) hides ds_read/MFMA/exp2 latency.
// R4 lesson: watch WRITE_SIZE for scratch-spill ballooning.

#define NN 8192
#define BHALF 4096
#define DIMK 128

typedef __bf16 bf16x8 __attribute__((ext_vector_type(8)));
typedef float f32x4 __attribute__((ext_vector_type(4)));

#define C1F 2.8853900817779268f   // 2*log2(e)
#define SCALEF 1.6986436f         // sqrt(C1)

// ---------------- Kernel A: normalize, scale by sqrt(C1), swizzle ----------
__global__ __launch_bounds__(256) void nt_normalize(
    const float* __restrict__ zi, const float* __restrict__ zj,
    unsigned int* __restrict__ zb_packed, float* __restrict__ out) {
  if (blockIdx.x == 0 && threadIdx.x == 0) out[0] = 0.0f;  // runs before finalize
  int row = blockIdx.x * 4 + (threadIdx.x >> 6);
  int lane = threadIdx.x & 63;
  const float* src = (row < BHALF) ? (zi + (size_t)row * DIMK)
                                   : (zj + (size_t)(row - BHALF) * DIMK);
  float2 v = ((const float2*)src)[lane];
  float ss = v.x * v.x + v.y * v.y;
#pragma unroll
  for (int off = 32; off >= 1; off >>= 1) ss += __shfl_xor(ss, off, 64);
  float rn = rsqrtf(ss) * SCALEF;
  __hip_bfloat16 h0 = __float2bfloat16(v.x * rn);
  __hip_bfloat16 h1 = __float2bfloat16(v.y * rn);
  unsigned int packed = ((unsigned int)(*(unsigned short*)&h1) << 16) |
                        (*(unsigned short*)&h0);
  int tile = row >> 4, t = row & 15;
  int cq = lane >> 2;               // chunk index 0..15 (= c*4 + quad)
  int c = cq >> 2, quad = cq & 3;
  size_t widx = ((size_t)((tile * 4 + c) * 64 + quad * 16 + t)) * 4 + (lane & 3);
  zb_packed[widx] = packed;
}

// ---------------- Kernel B: streaming sim + exp2 accumulation --------------
// Block = 4 waves x 64 rows = 256 rows; 128 cols (8 tiles) staged in LDS.
// Grid (64,32) = 2048 blocks; 4 blocks/CU -> exactly 2 generations.
// C/D: col=lane&15, row=quad*4+reg.
__global__ __launch_bounds__(256, 4) void nt_sim(
    const uint4* __restrict__ zbv, float* __restrict__ part) {
  __shared__ uint4 ldsb[2048];  // 32 KiB: B-span for this block's 128 cols

  const int lane = threadIdx.x & 63;
  const int wave = threadIdx.x >> 6;
  const int quad = lane >> 4;
  const int t = lane & 15;
  const int row_tile0 = blockIdx.y * 16 + wave * 4;

  // ---- async-stage the 32KB B-span: 32 chunks of 1KB, 8 instrs/wave ----
  {
    const char* gsrc = (const char*)zbv + (size_t)blockIdx.x * 32768;
#pragma unroll
    for (int k = 0; k < 8; ++k) {
      int chunk = k * 4 + wave;
      __builtin_amdgcn_global_load_lds(
          (const __attribute__((address_space(1))) unsigned int*)(
              gsrc + chunk * 1024 + lane * 16),
          (__attribute__((address_space(3))) unsigned int*)(
              (char*)ldsb + chunk * 1024),
          16, 0, 0);
    }
  }

  // ---- A fragments (persistent registers), overlaps with DMA ----
  bf16x8 A[4][4];  // [row-tile][K-chunk]
#pragma unroll
  for (int rt = 0; rt < 4; ++rt)
#pragma unroll
    for (int c = 0; c < 4; ++c)
      A[rt][c] = __builtin_bit_cast(
          bf16x8, zbv[(size_t)((row_tile0 + rt) * 4 + c) * 64 + lane]);

  float sum[4][4];
#pragma unroll
  for (int rt = 0; rt < 4; ++rt)
#pragma unroll
    for (int r = 0; r < 4; ++r) sum[rt][r] = 0.f;

  __syncthreads();  // DMA drain (vmcnt(0)) + join; only barrier in kernel

  // ---- compute loop: 8 col-tiles from LDS; unroll 1 keeps VGPR <= 128 ----
#pragma unroll 1
  for (int ct = 0; ct < 8; ++ct) {
    f32x4 acc[4];
#pragma unroll
    for (int rt = 0; rt < 4; ++rt) acc[rt] = (f32x4){0.f, 0.f, 0.f, 0.f};
#pragma unroll
    for (int c = 0; c < 4; ++c) {
      bf16x8 bv = __builtin_bit_cast(bf16x8, ldsb[(ct * 4 + c) * 64 + lane]);
#pragma unroll
      for (int rt = 0; rt < 4; ++rt)
        acc[rt] = __builtin_amdgcn_mfma_f32_16x16x32_bf16(A[rt][c], bv,
                                                          acc[rt], 0, 0, 0);
    }
#pragma unroll
    for (int rt = 0; rt < 4; ++rt)
#pragma unroll
      for (int r = 0; r < 4; ++r)
        sum[rt][r] += __builtin_amdgcn_exp2f(acc[rt][r]);
  }

  // reduce over the 16 col-lanes within each quad
#pragma unroll
  for (int off = 8; off >= 1; off >>= 1)
#pragma unroll
    for (int rt = 0; rt < 4; ++rt)
#pragma unroll
      for (int r = 0; r < 4; ++r)
        sum[rt][r] += __shfl_xor(sum[rt][r], off, 16);

  if (t == 0) {
    float* dst = part + (size_t)blockIdx.x * NN;
    int row_base = row_tile0 * 16;
#pragma unroll
    for (int rt = 0; rt < 4; ++rt)
#pragma unroll
      for (int r = 0; r < 4; ++r)
        dst[row_base + rt * 16 + quad * 4 + r] = sum[rt][r];
  }
}

// ---------------- Kernel C: finalize ----------------
__device__ __forceinline__ float bf2f(unsigned short s) {
  unsigned int u = (unsigned int)s << 16;
  return __builtin_bit_cast(float, u);
}

__global__ __launch_bounds__(256) void nt_finalize(
    const uint4* __restrict__ zbv, const float* __restrict__ part,
    float* __restrict__ out) {
  int i = blockIdx.x * 256 + threadIdx.x;
  int tile = i >> 4, t = i & 15;
  int p = i ^ BHALF;
  int tilep = p >> 4;
  float S = 0.f;
#pragma unroll 8
  for (int k = 0; k < 64; ++k) S += part[(size_t)k * NN + i];
  float dp = 0.f, dd = 0.f;
#pragma unroll
  for (int cq = 0; cq < 16; ++cq) {
    int c = cq >> 2, q = cq & 3;
    uint4 ua = zbv[(size_t)((tile * 4 + c) * 64 + q * 16 + t)];
    uint4 up = zbv[(size_t)((tilep * 4 + c) * 64 + q * 16 + t)];
    const unsigned short* pa = (const unsigned short*)&ua;
    const unsigned short* pp = (const unsigned short*)&up;
#pragma unroll
    for (int k = 0; k < 8; ++k) {
      float a = bf2f(pa[k]), pv = bf2f(pp[k]);
      dd = fmaf(a, a, dd);
      dp = fmaf(a, pv, dp);
    }
  }
  float diag = __builtin_amdgcn_exp2f(dd);        // exp2(C1 * d_ii)
  float v = logf(S - diag) - (2.0f / C1F) * dp;   // lse_i - pos_i
#pragma unroll
  for (int off = 32; off >= 1; off >>= 1) v += __shfl_xor(v, off, 64);
  __shared__ float wsum[4];
  if ((threadIdx.x & 63) == 0) wsum[threadIdx.x >> 6] = v;
  __syncthreads();
  if (threadIdx.x == 0)
    atomicAdd(out, (wsum[0] + wsum[1] + wsum[2] + wsum[3]) * (1.0f / (float)NN));
}

extern "C" void kernel_launch(void* const* d_in, const int* in_sizes, int n_in,
                              void* d_out, int out_size, void* d_ws,
                              size_t ws_size, hipStream_t stream) {
  const float* zi = (const float*)d_in[0];
  const float* zj = (const float*)d_in[1];

  // ws: zb swizzled bf16 (2 MiB) | part[64][8192] (2 MiB)
  unsigned int* zb = (unsigned int*)d_ws;
  float* part = (float*)((char*)d_ws + (2u << 20));

  nt_normalize<<<NN / 4, 256, 0, stream>>>(zi, zj, zb, (float*)d_out);

  dim3 grid(64, 32);  // 64 col-blocks x 128 cols, 32 row-blocks x 256 rows
  nt_sim<<<grid, 256, 0, stream>>>((const uint4*)zb, part);

  nt_finalize<<<NN / 256, 256, 0, stream>>>((const uint4*)zb, part,
                                            (float*)d_out);
}